// Round 1
// baseline (2832.067 us; speedup 1.0000x reference)
//
#include <hip/hip_runtime.h>

#define B_ 4
#define S_ 4096
#define IN_ 1024
#define H_ 16
#define D_ 64
#define OUT_ 1024
#define HD_ 1024   // H*D
#define M_ 16384   // B*S

typedef __bf16 bf16x8 __attribute__((ext_vector_type(8)));
typedef __bf16 bf16x2 __attribute__((ext_vector_type(2)));
typedef float floatx4 __attribute__((ext_vector_type(4)));

static __device__ __forceinline__ unsigned int f2bf(float f) {
    unsigned int u = __builtin_bit_cast(unsigned int, f);
    u += 0x7fffu + ((u >> 16) & 1u);   // round-to-nearest-even
    return u >> 16;
}

// v_dot2_f32_bf16: c += a.x*b.x + a.y*b.y  (bf16 pairs in, fp32 acc)
static __device__ __forceinline__ float dot2bf(unsigned int a, unsigned int b, float c) {
    return __builtin_amdgcn_fdot2_f32_bf16(__builtin_bit_cast(bf16x2, a),
                                           __builtin_bit_cast(bf16x2, b), c, false);
}

// ---------------- cast fp32 -> bf16, vectorized x4 ----------------
__global__ void cast_f32_bf16(const float* __restrict__ src,
                              unsigned short* __restrict__ dst, int n4) {
    int i = blockIdx.x * blockDim.x + threadIdx.x;
    if (i < n4) {
        float4 v = ((const float4*)src)[i];
        ushort4 o;
        o.x = (unsigned short)f2bf(v.x); o.y = (unsigned short)f2bf(v.y);
        o.z = (unsigned short)f2bf(v.z); o.w = (unsigned short)f2bf(v.w);
        ((ushort4*)dst)[i] = o;
    }
}

// ---------------- bf16 MFMA GEMM: C[M,N] = A[M,K] * B[N,K]^T ----------------
#define LSTR 40
__global__ __launch_bounds__(256) void gemm_bt(
    const unsigned short* __restrict__ A,   // [M,K] bf16
    const unsigned short* __restrict__ Bm,  // [N,K] bf16
    float* __restrict__ C, int M, int N, int K) {
    __shared__ unsigned short As[128 * LSTR];
    __shared__ unsigned short Bs[128 * LSTR];
    const int t = threadIdx.x;
    const int lane = t & 63;
    const int wave = t >> 6;
    const int wm = wave >> 1, wn = wave & 1;
    const int m0 = blockIdx.y * 128;
    const int n0 = blockIdx.x * 128;
    const int l16 = lane & 15;
    const int quad = lane >> 4;

    floatx4 acc[4][4];
#pragma unroll
    for (int i = 0; i < 4; i++)
#pragma unroll
        for (int j = 0; j < 4; j++) acc[i][j] = (floatx4){0.f, 0.f, 0.f, 0.f};

    for (int k0 = 0; k0 < K; k0 += 32) {
#pragma unroll
        for (int it = 0; it < 2; it++) {
            int c = it * 256 + t;
            int row = c >> 2;
            int kc = c & 3;
            uint4 va = *(const uint4*)(A + (size_t)(m0 + row) * K + k0 + kc * 8);
            *(uint4*)(As + row * LSTR + kc * 8) = va;
            uint4 vb = *(const uint4*)(Bm + (size_t)(n0 + row) * K + k0 + kc * 8);
            *(uint4*)(Bs + row * LSTR + kc * 8) = vb;
        }
        __syncthreads();
        bf16x8 af[4], bfr[4];
#pragma unroll
        for (int i = 0; i < 4; i++)
            af[i] = *(const bf16x8*)(As + (wm * 64 + i * 16 + l16) * LSTR + quad * 8);
#pragma unroll
        for (int j = 0; j < 4; j++)
            bfr[j] = *(const bf16x8*)(Bs + (wn * 64 + j * 16 + l16) * LSTR + quad * 8);
#pragma unroll
        for (int i = 0; i < 4; i++)
#pragma unroll
            for (int j = 0; j < 4; j++)
                acc[i][j] = __builtin_amdgcn_mfma_f32_16x16x32_bf16(
                    af[i], bfr[j], acc[i][j], 0, 0, 0);
        __syncthreads();
    }
#pragma unroll
    for (int i = 0; i < 4; i++)
#pragma unroll
        for (int j = 0; j < 4; j++)
#pragma unroll
            for (int r = 0; r < 4; r++) {
                int row = m0 + wm * 64 + i * 16 + quad * 4 + r;
                int col = n0 + wn * 64 + j * 16 + l16;
                C[(size_t)row * N + col] = acc[i][j][r];
            }
}

// ---------------- sequential RNN scan (v7: multi-wave co-residency) --------
// Same per-chain body as v6 (all-register, readlane broadcast, no LDS, no
// barriers), but now 4 blocks x 1024 threads: 16 waves per block MUST be
// co-resident on one CU -> 4 waves per SIMD. The ~255 cyc/step of dependent
// latency (DPP -> readlane -> 8-deep dot chain -> tanh) that a lone wave
// eats is now hidden by the hardware interleaving 4 independent chains per
// SIMD; the floor becomes pure VALU issue (~87 instr * 2cyc = ~174 cyc/step).
__global__ __launch_bounds__(1024, 1) void rnn_scan(
    const float* __restrict__ xp,      // [B,S,H,D] fp32 (GEMM1 output)
    const float* __restrict__ w_h,     // [H,D,D]
    const float* __restrict__ bias,    // [H,D]
    const float* __restrict__ h0,      // [B,H,D]
    unsigned short* __restrict__ y) {  // [B,S,H,D] bf16
    const int wave = threadIdx.x >> 6;
    const int e = threadIdx.x & 63;
    const int bh = blockIdx.x * 16 + wave;   // one chain per wave
    const int b = bh >> 4;
    const int h = bh & 15;

    // W[h][e][0..63] packed into 32 bf16-pair dwords
    unsigned int W2[32];
    const float* wrow = w_h + ((size_t)(h * 64 + e)) * 64;
#pragma unroll
    for (int j = 0; j < 16; j++) {
        float4 v = ((const float4*)wrow)[j];
        W2[2 * j]     = f2bf(v.x) | (f2bf(v.y) << 16);
        W2[2 * j + 1] = f2bf(v.z) | (f2bf(v.w) << 16);
    }
    const float be = bias[h * 64 + e];
    unsigned int hb = f2bf(h0[(b * 16 + h) * 64 + e]);   // bf16 state, 1/lane

    const float* xb = xp + ((size_t)(b * S_) * 16 + h) * 64 + e;  // + t*1024
    unsigned short* yb = y + ((size_t)(b * S_) * 16 + h) * 64 + e;

    float xA[8], xB[8];
#pragma unroll
    for (int i2 = 0; i2 < 8; i2++) xA[i2] = xb[(size_t)i2 * 1024];
#pragma unroll
    for (int i2 = 0; i2 < 8; i2++) xB[i2] = xb[(size_t)(8 + i2) * 1024];

    auto step = [&](int t, float xv) {
        // quad_perm [1,1,3,3] (0xF5): lane i gets h from lane i+1 (even i)
        // or its own (odd i) -> even lane 2k packs (h[2k], h[2k+1]).
        unsigned int hbs = (unsigned int)__builtin_amdgcn_update_dpp(
            0, (int)hb, 0xF5, 0xF, 0xF, true);
        unsigned int pk = (hbs << 16) | hb;
        float a0 = 0.f, a1 = 0.f, a2 = 0.f, a3 = 0.f;
#pragma unroll
        for (int k = 0; k < 8; k++) {
            // v_readlane -> SGPR: hardware broadcast, no LDS
            unsigned int s0 = (unsigned int)__builtin_amdgcn_readlane((int)pk, 8 * k + 0);
            unsigned int s1 = (unsigned int)__builtin_amdgcn_readlane((int)pk, 8 * k + 2);
            unsigned int s2 = (unsigned int)__builtin_amdgcn_readlane((int)pk, 8 * k + 4);
            unsigned int s3 = (unsigned int)__builtin_amdgcn_readlane((int)pk, 8 * k + 6);
            a0 = dot2bf(s0, W2[4 * k + 0], a0);
            a1 = dot2bf(s1, W2[4 * k + 1], a1);
            a2 = dot2bf(s2, W2[4 * k + 2], a2);
            a3 = dot2bf(s3, W2[4 * k + 3], a3);
        }
        float sum = (a0 + a1) + (a2 + a3);
        float pre = sum + (be + xv);
        // tanh: em = 2^(-2*log2e*|pre|); hn = sign * (1-em)/(1+em)
        float em = __builtin_amdgcn_exp2f(fabsf(pre) * -2.885390081777927f);
        float rr = (1.0f - em) * __builtin_amdgcn_rcpf(1.0f + em);
        float hn = copysignf(rr, pre);
        hb = f2bf(hn);
        yb[(size_t)t * 1024] = (unsigned short)hb;
    };

    for (int t0 = 0; t0 < S_; t0 += 16) {
#pragma unroll
        for (int u = 0; u < 8; u++) step(t0 + u, xA[u]);
        if (t0 + 16 < S_) {
#pragma unroll
            for (int i2 = 0; i2 < 8; i2++) xA[i2] = xb[(size_t)(t0 + 16 + i2) * 1024];
        }
#pragma unroll
        for (int u = 0; u < 8; u++) step(t0 + 8 + u, xB[u]);
        if (t0 + 24 < S_) {
#pragma unroll
            for (int i2 = 0; i2 < 8; i2++) xB[i2] = xb[(size_t)(t0 + 24 + i2) * 1024];
        }
    }
}

extern "C" void kernel_launch(void* const* d_in, const int* in_sizes, int n_in,
                              void* d_out, int out_size, void* d_ws, size_t ws_size,
                              hipStream_t stream) {
    const float* x     = (const float*)d_in[0];  // [B,S,IN]
    const float* h0    = (const float*)d_in[1];  // [B,H,D]
    const float* w_in  = (const float*)d_in[2];  // [HD,IN]
    const float* w_h   = (const float*)d_in[3];  // [H,D,D]
    const float* bias  = (const float*)d_in[4];  // [H,D]
    const float* w_out = (const float*)d_in[5];  // [OUT,HD]
    float* out = (float*)d_out;                  // [B,S,OUT] fp32; doubles as xp scratch

    char* ws = (char*)d_ws;
    unsigned short* x_bf    = (unsigned short*)(ws);                       // 33.5 MB
    unsigned short* win_bf  = (unsigned short*)(ws + (size_t)33554432);    // 2 MB
    unsigned short* wout_bf = (unsigned short*)(ws + (size_t)35651584);    // 2 MB
    unsigned short* y_bf    = (unsigned short*)(ws + (size_t)37748736);    // 33.5 MB

    {
        int n4 = (M_ * IN_) / 4;
        cast_f32_bf16<<<(n4 + 255) / 256, 256, 0, stream>>>(x, x_bf, n4);
        int w4 = (HD_ * IN_) / 4;
        cast_f32_bf16<<<(w4 + 255) / 256, 256, 0, stream>>>(w_in, win_bf, w4);
        cast_f32_bf16<<<(w4 + 255) / 256, 256, 0, stream>>>(w_out, wout_bf, w4);
    }
    // GEMM1: xp = x @ w_in^T  -> stored in d_out as scratch
    dim3 g1(HD_ / 128, M_ / 128);
    gemm_bt<<<g1, 256, 0, stream>>>(x_bf, win_bf, out, M_, HD_, IN_);
    // sequential scan: reads xp (d_out), writes y_bf
    // 4 blocks x 1024 threads = 16 waves/block forced onto one CU ->
    // 4 chains interleaved per SIMD to hide the serial-dependence latency.
    rnn_scan<<<4, 1024, 0, stream>>>(out, w_h, bias, h0, y_bf);
    // GEMM2: out = y @ w_out^T  -> overwrites d_out
    dim3 g2(OUT_ / 128, M_ / 128);
    gemm_bt<<<g2, 256, 0, stream>>>(y_bf, wout_bf, out, M_, OUT_, HD_);
}

// Round 2
// 1182.469 us; speedup vs baseline: 2.3950x; 2.3950x over previous
//
#include <hip/hip_runtime.h>

#define B_ 4
#define S_ 4096
#define IN_ 1024
#define H_ 16
#define D_ 64
#define OUT_ 1024
#define HD_ 1024   // H*D
#define M_ 16384   // B*S

typedef __bf16 bf16x8 __attribute__((ext_vector_type(8)));
typedef __bf16 bf16x2 __attribute__((ext_vector_type(2)));
typedef float floatx4 __attribute__((ext_vector_type(4)));
typedef int int32x4 __attribute__((ext_vector_type(4)));

static __device__ __forceinline__ unsigned int f2bf(float f) {
    unsigned int u = __builtin_bit_cast(unsigned int, f);
    u += 0x7fffu + ((u >> 16) & 1u);   // round-to-nearest-even
    return u >> 16;
}

// ---------------- cast fp32 -> bf16, vectorized x4 ----------------
__global__ void cast_f32_bf16(const float* __restrict__ src,
                              unsigned short* __restrict__ dst, int n4) {
    int i = blockIdx.x * blockDim.x + threadIdx.x;
    if (i < n4) {
        float4 v = ((const float4*)src)[i];
        ushort4 o;
        o.x = (unsigned short)f2bf(v.x); o.y = (unsigned short)f2bf(v.y);
        o.z = (unsigned short)f2bf(v.z); o.w = (unsigned short)f2bf(v.w);
        ((ushort4*)dst)[i] = o;
    }
}

// ---------------- bf16 MFMA GEMM: C[M,N] = A[M,K] * B[N,K]^T ----------------
#define LSTR 40
__global__ __launch_bounds__(256) void gemm_bt(
    const unsigned short* __restrict__ A,   // [M,K] bf16
    const unsigned short* __restrict__ Bm,  // [N,K] bf16
    float* __restrict__ C, int M, int N, int K) {
    __shared__ unsigned short As[128 * LSTR];
    __shared__ unsigned short Bs[128 * LSTR];
    const int t = threadIdx.x;
    const int lane = t & 63;
    const int wave = t >> 6;
    const int wm = wave >> 1, wn = wave & 1;
    const int m0 = blockIdx.y * 128;
    const int n0 = blockIdx.x * 128;
    const int l16 = lane & 15;
    const int quad = lane >> 4;

    floatx4 acc[4][4];
#pragma unroll
    for (int i = 0; i < 4; i++)
#pragma unroll
        for (int j = 0; j < 4; j++) acc[i][j] = (floatx4){0.f, 0.f, 0.f, 0.f};

    for (int k0 = 0; k0 < K; k0 += 32) {
#pragma unroll
        for (int it = 0; it < 2; it++) {
            int c = it * 256 + t;
            int row = c >> 2;
            int kc = c & 3;
            uint4 va = *(const uint4*)(A + (size_t)(m0 + row) * K + k0 + kc * 8);
            *(uint4*)(As + row * LSTR + kc * 8) = va;
            uint4 vb = *(const uint4*)(Bm + (size_t)(n0 + row) * K + k0 + kc * 8);
            *(uint4*)(Bs + row * LSTR + kc * 8) = vb;
        }
        __syncthreads();
        bf16x8 af[4], bfr[4];
#pragma unroll
        for (int i = 0; i < 4; i++)
            af[i] = *(const bf16x8*)(As + (wm * 64 + i * 16 + l16) * LSTR + quad * 8);
#pragma unroll
        for (int j = 0; j < 4; j++)
            bfr[j] = *(const bf16x8*)(Bs + (wn * 64 + j * 16 + l16) * LSTR + quad * 8);
#pragma unroll
        for (int i = 0; i < 4; i++)
#pragma unroll
            for (int j = 0; j < 4; j++)
                acc[i][j] = __builtin_amdgcn_mfma_f32_16x16x32_bf16(
                    af[i], bfr[j], acc[i][j], 0, 0, 0);
        __syncthreads();
    }
#pragma unroll
    for (int i = 0; i < 4; i++)
#pragma unroll
        for (int j = 0; j < 4; j++)
#pragma unroll
            for (int r = 0; r < 4; r++) {
                int row = m0 + wm * 64 + i * 16 + quad * 4 + r;
                int col = n0 + wn * 64 + j * 16 + l16;
                C[(size_t)row * N + col] = acc[i][j][r];
            }
}

// ---------------- sequential RNN scan (v8: MFMA matvec) ---------------------
// 64 blocks (one (b,h) chain), ONE wave, 1 wave/CU (R0 post-mortem: the
// readlane+dot2 body costs ~376cy ISSUE per step, so packing waves/SIMD
// serializes; the fix is fewer instructions). The 64x64 matvec (4096 MACs =
// 64 VALU ops) becomes 8 MFMAs (~40cy issue):
//   transposed orientation: A = h replicated into all 16 rows (8 ds_bpermute
//   from the even-lane packed bf16 pairs), B = W^T static fragments (32 VGPR),
//   y lands in lanes 0-15 acc[nt][0] -> spread to lane e via 4 bpermute +
//   3 cndmask, then the v6 tail (bias+x, tanh, f2bf, pack, store).
__global__ __launch_bounds__(64, 1) void rnn_scan(
    const float* __restrict__ xp,      // [B,S,H,D] fp32 (GEMM1 output)
    const float* __restrict__ w_h,     // [H,D,D]
    const float* __restrict__ bias,    // [H,D]
    const float* __restrict__ h0,      // [B,H,D]
    unsigned short* __restrict__ y) {  // [B,S,H,D] bf16
    const int bh = blockIdx.x;
    const int b = bh >> 4;
    const int h = bh & 15;
    const int e = threadIdx.x;
    const int c = e & 15;           // fragment column index
    const int q = e >> 4;           // 16-lane group
    const int q8 = q * 8;

    // ---- static W^T B-fragments: Bf[nt][kt], lane holds
    // W[nt*16 + c][kt*32 + q8 + j], j=0..7  (gemm_bt B-frag convention)
    auto loadB = [&](int nt, int kt) -> bf16x8 {
        const float* wr = w_h + ((size_t)(h * 64 + nt * 16 + c)) * 64 + kt * 32 + q8;
        float4 v0 = ((const float4*)wr)[0];
        float4 v1 = ((const float4*)wr)[1];
        int32x4 bi;
        bi[0] = (int)(f2bf(v0.x) | (f2bf(v0.y) << 16));
        bi[1] = (int)(f2bf(v0.z) | (f2bf(v0.w) << 16));
        bi[2] = (int)(f2bf(v1.x) | (f2bf(v1.y) << 16));
        bi[3] = (int)(f2bf(v1.z) | (f2bf(v1.w) << 16));
        return __builtin_bit_cast(bf16x8, bi);
    };
    const bf16x8 Bf00 = loadB(0, 0), Bf01 = loadB(0, 1);
    const bf16x8 Bf10 = loadB(1, 0), Bf11 = loadB(1, 1);
    const bf16x8 Bf20 = loadB(2, 0), Bf21 = loadB(2, 1);
    const bf16x8 Bf30 = loadB(3, 0), Bf31 = loadB(3, 1);

    // ---- static bpermute byte-addresses
    // A-frag: lane needs pair-dwords of h[(q8 + 2j) .. +1]; pairs live at
    // even lanes (lane 2m holds (h[2m], h[2m+1])) -> src lane = q8 + 2j (+32 for kt1)
    const int aA00 = (q8 + 0) * 4, aA01 = (q8 + 2) * 4,
              aA02 = (q8 + 4) * 4, aA03 = (q8 + 6) * 4;
    const int aA10 = aA00 + 128, aA11 = aA01 + 128,
              aA12 = aA02 + 128, aA13 = aA03 + 128;
    const int aY = c * 4;          // y-spread: lane e pulls from lane (e&15)
    const bool oddq = (q & 1) != 0;
    const bool hiq  = (q & 2) != 0;

    const float be = bias[h * 64 + e];
    unsigned int hb = f2bf(h0[(b * 16 + h) * 64 + e]);   // bf16 state, 1/lane

    const float* xb = xp + ((size_t)(b * S_) * 16 + h) * 64 + e;  // + t*1024
    unsigned short* yb = y + ((size_t)(b * S_) * 16 + h) * 64 + e;

    float xA[8], xB[8];
#pragma unroll
    for (int i2 = 0; i2 < 8; i2++) xA[i2] = xb[(size_t)i2 * 1024];
#pragma unroll
    for (int i2 = 0; i2 < 8; i2++) xB[i2] = xb[(size_t)(8 + i2) * 1024];

    auto step = [&](int t, float xv) {
        // quad_perm [1,1,3,3]: even lane 2m packs (h[2m], h[2m+1])
        unsigned int hbs = (unsigned int)__builtin_amdgcn_update_dpp(
            0, (int)hb, 0xF5, 0xF, 0xF, true);
        int pk = (int)((hbs << 16) | hb);
        // A fragments: h replicated into all 16 rows (addr depends on q only)
        int32x4 a0i, a1i;
        a0i[0] = __builtin_amdgcn_ds_bpermute(aA00, pk);
        a0i[1] = __builtin_amdgcn_ds_bpermute(aA01, pk);
        a0i[2] = __builtin_amdgcn_ds_bpermute(aA02, pk);
        a0i[3] = __builtin_amdgcn_ds_bpermute(aA03, pk);
        a1i[0] = __builtin_amdgcn_ds_bpermute(aA10, pk);
        a1i[1] = __builtin_amdgcn_ds_bpermute(aA11, pk);
        a1i[2] = __builtin_amdgcn_ds_bpermute(aA12, pk);
        a1i[3] = __builtin_amdgcn_ds_bpermute(aA13, pk);
        bf16x8 A0 = __builtin_bit_cast(bf16x8, a0i);
        bf16x8 A1 = __builtin_bit_cast(bf16x8, a1i);
        const floatx4 z4 = (floatx4){0.f, 0.f, 0.f, 0.f};
        // y[nt*16+c] = sum_k h[k] * W[nt*16+c][k]; 4 nt-tiles x 2 k-tiles
        floatx4 ac0 = __builtin_amdgcn_mfma_f32_16x16x32_bf16(A0, Bf00, z4, 0, 0, 0);
        floatx4 ac1 = __builtin_amdgcn_mfma_f32_16x16x32_bf16(A0, Bf10, z4, 0, 0, 0);
        floatx4 ac2 = __builtin_amdgcn_mfma_f32_16x16x32_bf16(A0, Bf20, z4, 0, 0, 0);
        floatx4 ac3 = __builtin_amdgcn_mfma_f32_16x16x32_bf16(A0, Bf30, z4, 0, 0, 0);
        ac0 = __builtin_amdgcn_mfma_f32_16x16x32_bf16(A1, Bf01, ac0, 0, 0, 0);
        ac1 = __builtin_amdgcn_mfma_f32_16x16x32_bf16(A1, Bf11, ac1, 0, 0, 0);
        ac2 = __builtin_amdgcn_mfma_f32_16x16x32_bf16(A1, Bf21, ac2, 0, 0, 0);
        ac3 = __builtin_amdgcn_mfma_f32_16x16x32_bf16(A1, Bf31, ac3, 0, 0, 0);
        // y lives in lanes 0-15, reg 0 of acc[nt] (row 0 of D). Spread: lane e
        // pulls acc[e>>4][0] from lane (e&15).
        float y0 = __builtin_bit_cast(float,
            __builtin_amdgcn_ds_bpermute(aY, __builtin_bit_cast(int, ac0[0])));
        float y1 = __builtin_bit_cast(float,
            __builtin_amdgcn_ds_bpermute(aY, __builtin_bit_cast(int, ac1[0])));
        float y2 = __builtin_bit_cast(float,
            __builtin_amdgcn_ds_bpermute(aY, __builtin_bit_cast(int, ac2[0])));
        float y3 = __builtin_bit_cast(float,
            __builtin_amdgcn_ds_bpermute(aY, __builtin_bit_cast(int, ac3[0])));
        float y01 = oddq ? y1 : y0;
        float y23 = oddq ? y3 : y2;
        float yv  = hiq ? y23 : y01;
        float pre = yv + (be + xv);
        // tanh: em = 2^(-2*log2e*|pre|); hn = sign * (1-em)/(1+em)
        float em = __builtin_amdgcn_exp2f(fabsf(pre) * -2.885390081777927f);
        float rr = (1.0f - em) * __builtin_amdgcn_rcpf(1.0f + em);
        float hn = copysignf(rr, pre);
        hb = f2bf(hn);
        yb[(size_t)t * 1024] = (unsigned short)hb;
    };

    for (int t0 = 0; t0 < S_; t0 += 16) {
#pragma unroll
        for (int u = 0; u < 8; u++) step(t0 + u, xA[u]);
        if (t0 + 16 < S_) {
#pragma unroll
            for (int i2 = 0; i2 < 8; i2++) xA[i2] = xb[(size_t)(t0 + 16 + i2) * 1024];
        }
#pragma unroll
        for (int u = 0; u < 8; u++) step(t0 + 8 + u, xB[u]);
        if (t0 + 24 < S_) {
#pragma unroll
            for (int i2 = 0; i2 < 8; i2++) xB[i2] = xb[(size_t)(t0 + 24 + i2) * 1024];
        }
    }
}

extern "C" void kernel_launch(void* const* d_in, const int* in_sizes, int n_in,
                              void* d_out, int out_size, void* d_ws, size_t ws_size,
                              hipStream_t stream) {
    const float* x     = (const float*)d_in[0];  // [B,S,IN]
    const float* h0    = (const float*)d_in[1];  // [B,H,D]
    const float* w_in  = (const float*)d_in[2];  // [HD,IN]
    const float* w_h   = (const float*)d_in[3];  // [H,D,D]
    const float* bias  = (const float*)d_in[4];  // [H,D]
    const float* w_out = (const float*)d_in[5];  // [OUT,HD]
    float* out = (float*)d_out;                  // [B,S,OUT] fp32; doubles as xp scratch

    char* ws = (char*)d_ws;
    unsigned short* x_bf    = (unsigned short*)(ws);                       // 33.5 MB
    unsigned short* win_bf  = (unsigned short*)(ws + (size_t)33554432);    // 2 MB
    unsigned short* wout_bf = (unsigned short*)(ws + (size_t)35651584);    // 2 MB
    unsigned short* y_bf    = (unsigned short*)(ws + (size_t)37748736);    // 33.5 MB

    {
        int n4 = (M_ * IN_) / 4;
        cast_f32_bf16<<<(n4 + 255) / 256, 256, 0, stream>>>(x, x_bf, n4);
        int w4 = (HD_ * IN_) / 4;
        cast_f32_bf16<<<(w4 + 255) / 256, 256, 0, stream>>>(w_in, win_bf, w4);
        cast_f32_bf16<<<(w4 + 255) / 256, 256, 0, stream>>>(w_out, wout_bf, w4);
    }
    // GEMM1: xp = x @ w_in^T  -> stored in d_out as scratch
    dim3 g1(HD_ / 128, M_ / 128);
    gemm_bt<<<g1, 256, 0, stream>>>(x_bf, win_bf, out, M_, HD_, IN_);
    // sequential scan: reads xp (d_out), writes y_bf (64 chains, 1 wave/CU)
    rnn_scan<<<64, 64, 0, stream>>>(out, w_h, bias, h0, y_bf);
    // GEMM2: out = y @ w_out^T  -> overwrites d_out
    dim3 g2(OUT_ / 128, M_ / 128);
    gemm_bt<<<g2, 256, 0, stream>>>(y_bf, wout_bf, out, M_, OUT_, HD_);
}

// Round 3
// 1062.914 us; speedup vs baseline: 2.6644x; 1.1125x over previous
//
#include <hip/hip_runtime.h>

#define B_ 4
#define S_ 4096
#define IN_ 1024
#define H_ 16
#define D_ 64
#define OUT_ 1024
#define HD_ 1024   // H*D
#define M_ 16384   // B*S

typedef __bf16 bf16x8 __attribute__((ext_vector_type(8)));
typedef __bf16 bf16x2 __attribute__((ext_vector_type(2)));
typedef float floatx4 __attribute__((ext_vector_type(4)));
typedef int int32x4 __attribute__((ext_vector_type(4)));

static __device__ __forceinline__ unsigned int f2bf(float f) {
    unsigned int u = __builtin_bit_cast(unsigned int, f);
    u += 0x7fffu + ((u >> 16) & 1u);   // round-to-nearest-even
    return u >> 16;
}

// ---------------- cast fp32 -> bf16, vectorized x4 ----------------
__global__ void cast_f32_bf16(const float* __restrict__ src,
                              unsigned short* __restrict__ dst, int n4) {
    int i = blockIdx.x * blockDim.x + threadIdx.x;
    if (i < n4) {
        float4 v = ((const float4*)src)[i];
        ushort4 o;
        o.x = (unsigned short)f2bf(v.x); o.y = (unsigned short)f2bf(v.y);
        o.z = (unsigned short)f2bf(v.z); o.w = (unsigned short)f2bf(v.w);
        ((ushort4*)dst)[i] = o;
    }
}

// ---------------- bf16 MFMA GEMM: C[M,N] = A[M,K] * B[N,K]^T ----------------
#define LSTR 40
__global__ __launch_bounds__(256) void gemm_bt(
    const unsigned short* __restrict__ A,   // [M,K] bf16
    const unsigned short* __restrict__ Bm,  // [N,K] bf16
    float* __restrict__ C, int M, int N, int K) {
    __shared__ unsigned short As[128 * LSTR];
    __shared__ unsigned short Bs[128 * LSTR];
    const int t = threadIdx.x;
    const int lane = t & 63;
    const int wave = t >> 6;
    const int wm = wave >> 1, wn = wave & 1;
    const int m0 = blockIdx.y * 128;
    const int n0 = blockIdx.x * 128;
    const int l16 = lane & 15;
    const int quad = lane >> 4;

    floatx4 acc[4][4];
#pragma unroll
    for (int i = 0; i < 4; i++)
#pragma unroll
        for (int j = 0; j < 4; j++) acc[i][j] = (floatx4){0.f, 0.f, 0.f, 0.f};

    for (int k0 = 0; k0 < K; k0 += 32) {
#pragma unroll
        for (int it = 0; it < 2; it++) {
            int c = it * 256 + t;
            int row = c >> 2;
            int kc = c & 3;
            uint4 va = *(const uint4*)(A + (size_t)(m0 + row) * K + k0 + kc * 8);
            *(uint4*)(As + row * LSTR + kc * 8) = va;
            uint4 vb = *(const uint4*)(Bm + (size_t)(n0 + row) * K + k0 + kc * 8);
            *(uint4*)(Bs + row * LSTR + kc * 8) = vb;
        }
        __syncthreads();
        bf16x8 af[4], bfr[4];
#pragma unroll
        for (int i = 0; i < 4; i++)
            af[i] = *(const bf16x8*)(As + (wm * 64 + i * 16 + l16) * LSTR + quad * 8);
#pragma unroll
        for (int j = 0; j < 4; j++)
            bfr[j] = *(const bf16x8*)(Bs + (wn * 64 + j * 16 + l16) * LSTR + quad * 8);
#pragma unroll
        for (int i = 0; i < 4; i++)
#pragma unroll
            for (int j = 0; j < 4; j++)
                acc[i][j] = __builtin_amdgcn_mfma_f32_16x16x32_bf16(
                    af[i], bfr[j], acc[i][j], 0, 0, 0);
        __syncthreads();
    }
#pragma unroll
    for (int i = 0; i < 4; i++)
#pragma unroll
        for (int j = 0; j < 4; j++)
#pragma unroll
            for (int r = 0; r < 4; r++) {
                int row = m0 + wm * 64 + i * 16 + quad * 4 + r;
                int col = n0 + wn * 64 + j * 16 + l16;
                C[(size_t)row * N + col] = acc[i][j][r];
            }
}

// ---------------- sequential RNN scan (v9: MFMA matvec, no y-spread) --------
// 64 blocks (one (b,h) chain), ONE wave, 1 wave/CU. v8 post-mortem: 544
// cyc/step, latency-bound with TWO serial ds_bpermute rounds. The y-spread
// round was redundant: A = h replicated into all 16 rows => all rows of D
// identical => EVERY lane holds y[nt*16 + (lane&15)] in all 4 regs of
// ac[nt]. Lane e = q*16+c needs y[e] = ac[q][0] -> 3 cndmask select on q,
// zero cross-lane ops. Also hoists be+x off the dependent path.
__global__ __launch_bounds__(64, 1) void rnn_scan(
    const float* __restrict__ xp,      // [B,S,H,D] fp32 (GEMM1 output)
    const float* __restrict__ w_h,     // [H,D,D]
    const float* __restrict__ bias,    // [H,D]
    const float* __restrict__ h0,      // [B,H,D]
    unsigned short* __restrict__ y) {  // [B,S,H,D] bf16
    const int bh = blockIdx.x;
    const int b = bh >> 4;
    const int h = bh & 15;
    const int e = threadIdx.x;
    const int c = e & 15;           // fragment column index
    const int q = e >> 4;           // 16-lane group
    const int q8 = q * 8;

    // ---- static W^T B-fragments: Bf[nt][kt], lane holds
    // W[nt*16 + c][kt*32 + q8 + j], j=0..7  (gemm_bt B-frag convention)
    auto loadB = [&](int nt, int kt) -> bf16x8 {
        const float* wr = w_h + ((size_t)(h * 64 + nt * 16 + c)) * 64 + kt * 32 + q8;
        float4 v0 = ((const float4*)wr)[0];
        float4 v1 = ((const float4*)wr)[1];
        int32x4 bi;
        bi[0] = (int)(f2bf(v0.x) | (f2bf(v0.y) << 16));
        bi[1] = (int)(f2bf(v0.z) | (f2bf(v0.w) << 16));
        bi[2] = (int)(f2bf(v1.x) | (f2bf(v1.y) << 16));
        bi[3] = (int)(f2bf(v1.z) | (f2bf(v1.w) << 16));
        return __builtin_bit_cast(bf16x8, bi);
    };
    const bf16x8 Bf00 = loadB(0, 0), Bf01 = loadB(0, 1);
    const bf16x8 Bf10 = loadB(1, 0), Bf11 = loadB(1, 1);
    const bf16x8 Bf20 = loadB(2, 0), Bf21 = loadB(2, 1);
    const bf16x8 Bf30 = loadB(3, 0), Bf31 = loadB(3, 1);

    // ---- static bpermute byte-addresses for the A-frag gather
    // pair p = (h[2p],h[2p+1]) lives (packed) at lane 2p; group q needs
    // pairs q*4+j (A0, k=0..31) and 16+q*4+j (A1, k=32..63).
    const int aA00 = (q8 + 0) * 4, aA01 = (q8 + 2) * 4,
              aA02 = (q8 + 4) * 4, aA03 = (q8 + 6) * 4;
    const int aA10 = aA00 + 128, aA11 = aA01 + 128,
              aA12 = aA02 + 128, aA13 = aA03 + 128;
    const bool q1 = (q & 1) != 0;
    const bool q2 = (q & 2) != 0;

    const float be = bias[h * 64 + e];
    unsigned int hb = f2bf(h0[(b * 16 + h) * 64 + e]);   // bf16 state, 1/lane

    const float* xb = xp + ((size_t)(b * S_) * 16 + h) * 64 + e;  // + t*1024
    unsigned short* yb = y + ((size_t)(b * S_) * 16 + h) * 64 + e;

    // prefetched bias+x (off the dependent path)
    float bxA[8], bxB[8];
#pragma unroll
    for (int i2 = 0; i2 < 8; i2++) bxA[i2] = be + xb[(size_t)i2 * 1024];
#pragma unroll
    for (int i2 = 0; i2 < 8; i2++) bxB[i2] = be + xb[(size_t)(8 + i2) * 1024];

    auto step = [&](int t, float bx) {
        // quad_perm [1,1,3,3]: even lane 2m packs (h[2m], h[2m+1])
        unsigned int hbs = (unsigned int)__builtin_amdgcn_update_dpp(
            0, (int)hb, 0xF5, 0xF, 0xF, true);
        int pk = (int)((hbs << 16) | hb);
        // A fragments: h replicated into all 16 rows (addr depends on q only)
        int32x4 a0i, a1i;
        a0i[0] = __builtin_amdgcn_ds_bpermute(aA00, pk);
        a0i[1] = __builtin_amdgcn_ds_bpermute(aA01, pk);
        a0i[2] = __builtin_amdgcn_ds_bpermute(aA02, pk);
        a0i[3] = __builtin_amdgcn_ds_bpermute(aA03, pk);
        a1i[0] = __builtin_amdgcn_ds_bpermute(aA10, pk);
        a1i[1] = __builtin_amdgcn_ds_bpermute(aA11, pk);
        a1i[2] = __builtin_amdgcn_ds_bpermute(aA12, pk);
        a1i[3] = __builtin_amdgcn_ds_bpermute(aA13, pk);
        bf16x8 A0 = __builtin_bit_cast(bf16x8, a0i);
        bf16x8 A1 = __builtin_bit_cast(bf16x8, a1i);
        const floatx4 z4 = (floatx4){0.f, 0.f, 0.f, 0.f};
        // y[nt*16+c] = sum_k h[k] * W[nt*16+c][k]; 4 nt-tiles x 2 k-tiles
        floatx4 ac0 = __builtin_amdgcn_mfma_f32_16x16x32_bf16(A0, Bf00, z4, 0, 0, 0);
        floatx4 ac1 = __builtin_amdgcn_mfma_f32_16x16x32_bf16(A0, Bf10, z4, 0, 0, 0);
        floatx4 ac2 = __builtin_amdgcn_mfma_f32_16x16x32_bf16(A0, Bf20, z4, 0, 0, 0);
        floatx4 ac3 = __builtin_amdgcn_mfma_f32_16x16x32_bf16(A0, Bf30, z4, 0, 0, 0);
        ac0 = __builtin_amdgcn_mfma_f32_16x16x32_bf16(A1, Bf01, ac0, 0, 0, 0);
        ac1 = __builtin_amdgcn_mfma_f32_16x16x32_bf16(A1, Bf11, ac1, 0, 0, 0);
        ac2 = __builtin_amdgcn_mfma_f32_16x16x32_bf16(A1, Bf21, ac2, 0, 0, 0);
        ac3 = __builtin_amdgcn_mfma_f32_16x16x32_bf16(A1, Bf31, ac3, 0, 0, 0);
        // A rows identical => D rows identical => lane e already holds
        // y[nt*16+c] in ac[nt][0] for every nt. Select nt = q (3 cndmask).
        float y01 = q1 ? ac1[0] : ac0[0];
        float y23 = q1 ? ac3[0] : ac2[0];
        float yv  = q2 ? y23 : y01;
        float pre = yv + bx;
        // tanh: em = 2^(-2*log2e*|pre|); hn = sign * (1-em)/(1+em)
        float em = __builtin_amdgcn_exp2f(fabsf(pre) * -2.885390081777927f);
        float rr = (1.0f - em) * __builtin_amdgcn_rcpf(1.0f + em);
        float hn = copysignf(rr, pre);
        hb = f2bf(hn);
        yb[(size_t)t * 1024] = (unsigned short)hb;
    };

    for (int t0 = 0; t0 < S_; t0 += 16) {
#pragma unroll
        for (int u = 0; u < 8; u++) step(t0 + u, bxA[u]);
        if (t0 + 16 < S_) {
#pragma unroll
            for (int i2 = 0; i2 < 8; i2++) bxA[i2] = be + xb[(size_t)(t0 + 16 + i2) * 1024];
        }
#pragma unroll
        for (int u = 0; u < 8; u++) step(t0 + 8 + u, bxB[u]);
        if (t0 + 24 < S_) {
#pragma unroll
            for (int i2 = 0; i2 < 8; i2++) bxB[i2] = be + xb[(size_t)(t0 + 24 + i2) * 1024];
        }
    }
}

extern "C" void kernel_launch(void* const* d_in, const int* in_sizes, int n_in,
                              void* d_out, int out_size, void* d_ws, size_t ws_size,
                              hipStream_t stream) {
    const float* x     = (const float*)d_in[0];  // [B,S,IN]
    const float* h0    = (const float*)d_in[1];  // [B,H,D]
    const float* w_in  = (const float*)d_in[2];  // [HD,IN]
    const float* w_h   = (const float*)d_in[3];  // [H,D,D]
    const float* bias  = (const float*)d_in[4];  // [H,D]
    const float* w_out = (const float*)d_in[5];  // [OUT,HD]
    float* out = (float*)d_out;                  // [B,S,OUT] fp32; doubles as xp scratch

    char* ws = (char*)d_ws;
    unsigned short* x_bf    = (unsigned short*)(ws);                       // 33.5 MB
    unsigned short* win_bf  = (unsigned short*)(ws + (size_t)33554432);    // 2 MB
    unsigned short* wout_bf = (unsigned short*)(ws + (size_t)35651584);    // 2 MB
    unsigned short* y_bf    = (unsigned short*)(ws + (size_t)37748736);    // 33.5 MB

    {
        int n4 = (M_ * IN_) / 4;
        cast_f32_bf16<<<(n4 + 255) / 256, 256, 0, stream>>>(x, x_bf, n4);
        int w4 = (HD_ * IN_) / 4;
        cast_f32_bf16<<<(w4 + 255) / 256, 256, 0, stream>>>(w_in, win_bf, w4);
        cast_f32_bf16<<<(w4 + 255) / 256, 256, 0, stream>>>(w_out, wout_bf, w4);
    }
    // GEMM1: xp = x @ w_in^T  -> stored in d_out as scratch
    dim3 g1(HD_ / 128, M_ / 128);
    gemm_bt<<<g1, 256, 0, stream>>>(x_bf, win_bf, out, M_, HD_, IN_);
    // sequential scan: reads xp (d_out), writes y_bf (64 chains, 1 wave/CU)
    rnn_scan<<<64, 64, 0, stream>>>(out, w_h, bias, h0, y_bf);
    // GEMM2: out = y @ w_out^T  -> overwrites d_out
    dim3 g2(OUT_ / 128, M_ / 128);
    gemm_bt<<<g2, 256, 0, stream>>>(y_bf, wout_bf, out, M_, OUT_, HD_);
}

// Round 5
// 990.431 us; speedup vs baseline: 2.8594x; 1.0732x over previous
//
#include <hip/hip_runtime.h>

#define B_ 4
#define S_ 4096
#define IN_ 1024
#define H_ 16
#define D_ 64
#define OUT_ 1024
#define HD_ 1024   // H*D
#define M_ 16384   // B*S

typedef __bf16 bf16x8 __attribute__((ext_vector_type(8)));
typedef __bf16 bf16x2 __attribute__((ext_vector_type(2)));
typedef float floatx4 __attribute__((ext_vector_type(4)));
typedef int int32x4 __attribute__((ext_vector_type(4)));

static __device__ __forceinline__ unsigned int f2bf(float f) {
    unsigned int u = __builtin_bit_cast(unsigned int, f);
    u += 0x7fffu + ((u >> 16) & 1u);   // round-to-nearest-even
    return u >> 16;
}

// ---------------- cast fp32 -> bf16, vectorized x4 ----------------
__global__ void cast_f32_bf16(const float* __restrict__ src,
                              unsigned short* __restrict__ dst, int n4) {
    int i = blockIdx.x * blockDim.x + threadIdx.x;
    if (i < n4) {
        float4 v = ((const float4*)src)[i];
        ushort4 o;
        o.x = (unsigned short)f2bf(v.x); o.y = (unsigned short)f2bf(v.y);
        o.z = (unsigned short)f2bf(v.z); o.w = (unsigned short)f2bf(v.w);
        ((ushort4*)dst)[i] = o;
    }
}

// ---------------- bf16 MFMA GEMM: C[M,N] = A[M,K] * B[N,K]^T ----------------
#define LSTR 40
__global__ __launch_bounds__(256) void gemm_bt(
    const unsigned short* __restrict__ A,   // [M,K] bf16
    const unsigned short* __restrict__ Bm,  // [N,K] bf16
    float* __restrict__ C, int M, int N, int K) {
    __shared__ unsigned short As[128 * LSTR];
    __shared__ unsigned short Bs[128 * LSTR];
    const int t = threadIdx.x;
    const int lane = t & 63;
    const int wave = t >> 6;
    const int wm = wave >> 1, wn = wave & 1;
    const int m0 = blockIdx.y * 128;
    const int n0 = blockIdx.x * 128;
    const int l16 = lane & 15;
    const int quad = lane >> 4;

    floatx4 acc[4][4];
#pragma unroll
    for (int i = 0; i < 4; i++)
#pragma unroll
        for (int j = 0; j < 4; j++) acc[i][j] = (floatx4){0.f, 0.f, 0.f, 0.f};

    for (int k0 = 0; k0 < K; k0 += 32) {
#pragma unroll
        for (int it = 0; it < 2; it++) {
            int c = it * 256 + t;
            int row = c >> 2;
            int kc = c & 3;
            uint4 va = *(const uint4*)(A + (size_t)(m0 + row) * K + k0 + kc * 8);
            *(uint4*)(As + row * LSTR + kc * 8) = va;
            uint4 vb = *(const uint4*)(Bm + (size_t)(n0 + row) * K + k0 + kc * 8);
            *(uint4*)(Bs + row * LSTR + kc * 8) = vb;
        }
        __syncthreads();
        bf16x8 af[4], bfr[4];
#pragma unroll
        for (int i = 0; i < 4; i++)
            af[i] = *(const bf16x8*)(As + (wm * 64 + i * 16 + l16) * LSTR + quad * 8);
#pragma unroll
        for (int j = 0; j < 4; j++)
            bfr[j] = *(const bf16x8*)(Bs + (wn * 64 + j * 16 + l16) * LSTR + quad * 8);
#pragma unroll
        for (int i = 0; i < 4; i++)
#pragma unroll
            for (int j = 0; j < 4; j++)
                acc[i][j] = __builtin_amdgcn_mfma_f32_16x16x32_bf16(
                    af[i], bfr[j], acc[i][j], 0, 0, 0);
        __syncthreads();
    }
#pragma unroll
    for (int i = 0; i < 4; i++)
#pragma unroll
        for (int j = 0; j < 4; j++)
#pragma unroll
            for (int r = 0; r < 4; r++) {
                int row = m0 + wm * 64 + i * 16 + quad * 4 + r;
                int col = n0 + wn * 64 + j * 16 + l16;
                C[(size_t)row * N + col] = acc[i][j][r];
            }
}

// ---------------- sequential RNN scan (v10: DPP-only broadcast) -------------
// 64 blocks (one (b,h) chain), ONE wave, 1 wave/CU. v9 post-mortem: 474
// cyc/step, latency-bound; the remaining ds_bpermute round (8 ops +
// lgkmcnt(0)) is ~100cy of the path. Fix: the MFMA k-slot assignment is
// invariant under any row-uniform permutation pi of k as long as W's
// B-frags use the same pi. Choose pi(q*8+j) = 16q+j (A0) / 16q+8+j (A1):
// group q supplies h[16q..16q+15], which lives IN ROW q. The gather becomes
// 8x DPP row_newbcast (VALU pipe, no lgkmcnt) of the quad-packed pairs.
// Also: the two k-half MFMAs are now independent (acA, acB) + 1 fp add,
// halving the MFMA-layer latency.
__global__ __launch_bounds__(64, 1) void rnn_scan(
    const float* __restrict__ xp,      // [B,S,H,D] fp32 (GEMM1 output)
    const float* __restrict__ w_h,     // [H,D,D]
    const float* __restrict__ bias,    // [H,D]
    const float* __restrict__ h0,      // [B,H,D]
    unsigned short* __restrict__ y) {  // [B,S,H,D] bf16
    const int bh = blockIdx.x;
    const int b = bh >> 4;
    const int h = bh & 15;
    const int e = threadIdx.x;
    const int c = e & 15;           // fragment column index
    const int q = e >> 4;           // 16-lane group (row)

    // ---- static W^T B-fragments under pi: lane (q,c) of BfA[nt] holds
    // W[nt*16+c][16q + j], of BfB[nt] holds W[nt*16+c][16q + 8 + j], j=0..7.
    auto loadB = [&](int nt, int koff) -> bf16x8 {
        const float* wr = w_h + ((size_t)(h * 64 + nt * 16 + c)) * 64 + q * 16 + koff;
        float4 v0 = ((const float4*)wr)[0];
        float4 v1 = ((const float4*)wr)[1];
        int32x4 bi;
        bi[0] = (int)(f2bf(v0.x) | (f2bf(v0.y) << 16));
        bi[1] = (int)(f2bf(v0.z) | (f2bf(v0.w) << 16));
        bi[2] = (int)(f2bf(v1.x) | (f2bf(v1.y) << 16));
        bi[3] = (int)(f2bf(v1.z) | (f2bf(v1.w) << 16));
        return __builtin_bit_cast(bf16x8, bi);
    };
    const bf16x8 BfA0 = loadB(0, 0), BfB0 = loadB(0, 8);
    const bf16x8 BfA1 = loadB(1, 0), BfB1 = loadB(1, 8);
    const bf16x8 BfA2 = loadB(2, 0), BfB2 = loadB(2, 8);
    const bf16x8 BfA3 = loadB(3, 0), BfB3 = loadB(3, 8);

    const bool q1 = (q & 1) != 0;
    const bool q2 = (q & 2) != 0;

    const float be = bias[h * 64 + e];
    unsigned int hb = f2bf(h0[(b * 16 + h) * 64 + e]);   // bf16 state, 1/lane

    const float* xb = xp + ((size_t)(b * S_) * 16 + h) * 64 + e;  // + t*1024
    unsigned short* yb = y + ((size_t)(b * S_) * 16 + h) * 64 + e;

    // prefetched bias+x (off the dependent path)
    float bxA[8], bxB[8];
#pragma unroll
    for (int i2 = 0; i2 < 8; i2++) bxA[i2] = be + xb[(size_t)i2 * 1024];
#pragma unroll
    for (int i2 = 0; i2 < 8; i2++) bxB[i2] = be + xb[(size_t)(8 + i2) * 1024];

    auto step = [&](int t, float bx) {
        // quad_perm [1,1,3,3]: even lane 2d (in row q) packs
        // pk = (h[16q+2d+1]<<16) | h[16q+2d]
        unsigned int hbs = (unsigned int)__builtin_amdgcn_update_dpp(
            0, (int)hb, 0xF5, 0xF, 0xF, true);
        int pk = (int)((hbs << 16) | hb);
        // row_newbcast:N (DPP ctrl 0x150+N): broadcast lane N of each 16-row
        // to the whole row. A-frag dword d = pair at even lane 2d (A0) /
        // 8+2d (A1). Pure VALU: no LDS pipe, no lgkmcnt on the serial path.
        int32x4 a0i, a1i;
        a0i[0] = __builtin_amdgcn_update_dpp(0, pk, 0x150 + 0,  0xF, 0xF, true);
        a0i[1] = __builtin_amdgcn_update_dpp(0, pk, 0x150 + 2,  0xF, 0xF, true);
        a0i[2] = __builtin_amdgcn_update_dpp(0, pk, 0x150 + 4,  0xF, 0xF, true);
        a0i[3] = __builtin_amdgcn_update_dpp(0, pk, 0x150 + 6,  0xF, 0xF, true);
        a1i[0] = __builtin_amdgcn_update_dpp(0, pk, 0x150 + 8,  0xF, 0xF, true);
        a1i[1] = __builtin_amdgcn_update_dpp(0, pk, 0x150 + 10, 0xF, 0xF, true);
        a1i[2] = __builtin_amdgcn_update_dpp(0, pk, 0x150 + 12, 0xF, 0xF, true);
        a1i[3] = __builtin_amdgcn_update_dpp(0, pk, 0x150 + 14, 0xF, 0xF, true);
        bf16x8 A0 = __builtin_bit_cast(bf16x8, a0i);   // h[16q + 0..7]
        bf16x8 A1 = __builtin_bit_cast(bf16x8, a1i);   // h[16q + 8..15]
        const floatx4 z4 = (floatx4){0.f, 0.f, 0.f, 0.f};
        // y[nt*16+c] = sum over k-half A (pi: 16q+j) + k-half B (16q+8+j);
        // the two halves are INDEPENDENT MFMAs, summed by 1 fp add after
        // the nt-select (halves the MFMA-layer latency vs chaining).
        floatx4 acA0 = __builtin_amdgcn_mfma_f32_16x16x32_bf16(A0, BfA0, z4, 0, 0, 0);
        floatx4 acB0 = __builtin_amdgcn_mfma_f32_16x16x32_bf16(A1, BfB0, z4, 0, 0, 0);
        floatx4 acA1 = __builtin_amdgcn_mfma_f32_16x16x32_bf16(A0, BfA1, z4, 0, 0, 0);
        floatx4 acB1 = __builtin_amdgcn_mfma_f32_16x16x32_bf16(A1, BfB1, z4, 0, 0, 0);
        floatx4 acA2 = __builtin_amdgcn_mfma_f32_16x16x32_bf16(A0, BfA2, z4, 0, 0, 0);
        floatx4 acB2 = __builtin_amdgcn_mfma_f32_16x16x32_bf16(A1, BfB2, z4, 0, 0, 0);
        floatx4 acA3 = __builtin_amdgcn_mfma_f32_16x16x32_bf16(A0, BfA3, z4, 0, 0, 0);
        floatx4 acB3 = __builtin_amdgcn_mfma_f32_16x16x32_bf16(A1, BfB3, z4, 0, 0, 0);
        // A rows identical => D rows identical => lane e holds y-half in
        // ac*[nt][0] for every nt. Select nt = q (3 cndmask each) + add.
        float yA01 = q1 ? acA1[0] : acA0[0];
        float yA23 = q1 ? acA3[0] : acA2[0];
        float yA   = q2 ? yA23 : yA01;
        float yB01 = q1 ? acB1[0] : acB0[0];
        float yB23 = q1 ? acB3[0] : acB2[0];
        float yB   = q2 ? yB23 : yB01;
        float pre = (yA + yB) + bx;
        // tanh: em = 2^(-2*log2e*|pre|); hn = sign * (1-em)/(1+em)
        float em = __builtin_amdgcn_exp2f(fabsf(pre) * -2.885390081777927f);
        float rr = (1.0f - em) * __builtin_amdgcn_rcpf(1.0f + em);
        float hn = copysignf(rr, pre);
        hb = f2bf(hn);
        yb[(size_t)t * 1024] = (unsigned short)hb;
    };

    for (int t0 = 0; t0 < S_; t0 += 16) {
#pragma unroll
        for (int u = 0; u < 8; u++) step(t0 + u, bxA[u]);
        if (t0 + 16 < S_) {
#pragma unroll
            for (int i2 = 0; i2 < 8; i2++) bxA[i2] = be + xb[(size_t)(t0 + 16 + i2) * 1024];
        }
#pragma unroll
        for (int u = 0; u < 8; u++) step(t0 + 8 + u, bxB[u]);
        if (t0 + 24 < S_) {
#pragma unroll
            for (int i2 = 0; i2 < 8; i2++) bxB[i2] = be + xb[(size_t)(t0 + 24 + i2) * 1024];
        }
    }
}

extern "C" void kernel_launch(void* const* d_in, const int* in_sizes, int n_in,
                              void* d_out, int out_size, void* d_ws, size_t ws_size,
                              hipStream_t stream) {
    const float* x     = (const float*)d_in[0];  // [B,S,IN]
    const float* h0    = (const float*)d_in[1];  // [B,H,D]
    const float* w_in  = (const float*)d_in[2];  // [HD,IN]
    const float* w_h   = (const float*)d_in[3];  // [H,D,D]
    const float* bias  = (const float*)d_in[4];  // [H,D]
    const float* w_out = (const float*)d_in[5];  // [OUT,HD]
    float* out = (float*)d_out;                  // [B,S,OUT] fp32; doubles as xp scratch

    char* ws = (char*)d_ws;
    unsigned short* x_bf    = (unsigned short*)(ws);                       // 33.5 MB
    unsigned short* win_bf  = (unsigned short*)(ws + (size_t)33554432);    // 2 MB
    unsigned short* wout_bf = (unsigned short*)(ws + (size_t)35651584);    // 2 MB
    unsigned short* y_bf    = (unsigned short*)(ws + (size_t)37748736);    // 33.5 MB

    {
        int n4 = (M_ * IN_) / 4;
        cast_f32_bf16<<<(n4 + 255) / 256, 256, 0, stream>>>(x, x_bf, n4);
        int w4 = (HD_ * IN_) / 4;
        cast_f32_bf16<<<(w4 + 255) / 256, 256, 0, stream>>>(w_in, win_bf, w4);
        cast_f32_bf16<<<(w4 + 255) / 256, 256, 0, stream>>>(w_out, wout_bf, w4);
    }
    // GEMM1: xp = x @ w_in^T  -> stored in d_out as scratch
    dim3 g1(HD_ / 128, M_ / 128);
    gemm_bt<<<g1, 256, 0, stream>>>(x_bf, win_bf, out, M_, HD_, IN_);
    // sequential scan: reads xp (d_out), writes y_bf (64 chains, 1 wave/CU)
    rnn_scan<<<64, 64, 0, stream>>>(out, w_h, bias, h0, y_bf);
    // GEMM2: out = y @ w_out^T  -> overwrites d_out
    dim3 g2(OUT_ / 128, M_ / 128);
    gemm_bt<<<g2, 256, 0, stream>>>(y_bf, wout_bf, out, M_, OUT_, HD_);
}

// Round 6
// 960.965 us; speedup vs baseline: 2.9471x; 1.0307x over previous
//
#include <hip/hip_runtime.h>

#define B_ 4
#define S_ 4096
#define IN_ 1024
#define H_ 16
#define D_ 64
#define OUT_ 1024
#define HD_ 1024   // H*D
#define M_ 16384   // B*S

typedef __bf16 bf16x8 __attribute__((ext_vector_type(8)));
typedef __bf16 bf16x2 __attribute__((ext_vector_type(2)));
typedef float floatx4 __attribute__((ext_vector_type(4)));
typedef int int32x4 __attribute__((ext_vector_type(4)));

#define TWO_LOG2E 2.885390081777927f   // 2*log2(e)

static __device__ __forceinline__ unsigned int f2bf(float f) {
    unsigned int u = __builtin_bit_cast(unsigned int, f);
    u += 0x7fffu + ((u >> 16) & 1u);   // round-to-nearest-even
    return u >> 16;
}

// ---------------- cast fp32 -> bf16, vectorized x4 ----------------
__global__ void cast_f32_bf16(const float* __restrict__ src,
                              unsigned short* __restrict__ dst, int n4) {
    int i = blockIdx.x * blockDim.x + threadIdx.x;
    if (i < n4) {
        float4 v = ((const float4*)src)[i];
        ushort4 o;
        o.x = (unsigned short)f2bf(v.x); o.y = (unsigned short)f2bf(v.y);
        o.z = (unsigned short)f2bf(v.z); o.w = (unsigned short)f2bf(v.w);
        ((ushort4*)dst)[i] = o;
    }
}

// ---------------- bf16 MFMA GEMM: C[M,N] = A[M,K] * B[N,K]^T ----------------
#define LSTR 40
__global__ __launch_bounds__(256) void gemm_bt(
    const unsigned short* __restrict__ A,   // [M,K] bf16
    const unsigned short* __restrict__ Bm,  // [N,K] bf16
    float* __restrict__ C, int M, int N, int K) {
    __shared__ unsigned short As[128 * LSTR];
    __shared__ unsigned short Bs[128 * LSTR];
    const int t = threadIdx.x;
    const int lane = t & 63;
    const int wave = t >> 6;
    const int wm = wave >> 1, wn = wave & 1;
    const int m0 = blockIdx.y * 128;
    const int n0 = blockIdx.x * 128;
    const int l16 = lane & 15;
    const int quad = lane >> 4;

    floatx4 acc[4][4];
#pragma unroll
    for (int i = 0; i < 4; i++)
#pragma unroll
        for (int j = 0; j < 4; j++) acc[i][j] = (floatx4){0.f, 0.f, 0.f, 0.f};

    for (int k0 = 0; k0 < K; k0 += 32) {
#pragma unroll
        for (int it = 0; it < 2; it++) {
            int c = it * 256 + t;
            int row = c >> 2;
            int kc = c & 3;
            uint4 va = *(const uint4*)(A + (size_t)(m0 + row) * K + k0 + kc * 8);
            *(uint4*)(As + row * LSTR + kc * 8) = va;
            uint4 vb = *(const uint4*)(Bm + (size_t)(n0 + row) * K + k0 + kc * 8);
            *(uint4*)(Bs + row * LSTR + kc * 8) = vb;
        }
        __syncthreads();
        bf16x8 af[4], bfr[4];
#pragma unroll
        for (int i = 0; i < 4; i++)
            af[i] = *(const bf16x8*)(As + (wm * 64 + i * 16 + l16) * LSTR + quad * 8);
#pragma unroll
        for (int j = 0; j < 4; j++)
            bfr[j] = *(const bf16x8*)(Bs + (wn * 64 + j * 16 + l16) * LSTR + quad * 8);
#pragma unroll
        for (int i = 0; i < 4; i++)
#pragma unroll
            for (int j = 0; j < 4; j++)
                acc[i][j] = __builtin_amdgcn_mfma_f32_16x16x32_bf16(
                    af[i], bfr[j], acc[i][j], 0, 0, 0);
        __syncthreads();
    }
#pragma unroll
    for (int i = 0; i < 4; i++)
#pragma unroll
        for (int j = 0; j < 4; j++)
#pragma unroll
            for (int r = 0; r < 4; r++) {
                int row = m0 + wm * 64 + i * 16 + quad * 4 + r;
                int col = n0 + wn * 64 + j * 16 + l16;
                C[(size_t)row * N + col] = acc[i][j][r];
            }
}

// ---------------- sequential RNN scan (v11: short-chain step) ---------------
// 64 blocks (one (b,h) chain), ONE wave, 1 wave/CU. v10 post-mortem: 433
// cyc/step, ~340 cyc is dependent-op latency across ~19 serial layers.
// Wall time = 4096 * step latency (packing chains can't help) -> remove
// serial layers:
//  1. W,bias,x statically scaled by 2*log2e (off-path)   -> no mul layer
//  2. tanh(x) = 1 - 2/(exp2(pre')+1): exp2,add,rcp,fma   -> no abs/copysign
//  3. h kept f32; quad_perm(f32) + v_cvt_pk_bf16_f32     -> no f2bf+pack
//     (store-side f2bf moved OFF the critical path)
//  4. bias+x preloaded into MFMA C reg0 (all 4 A-half MFMAs carry the
//     lane's own bx; only the selected nt=q slot is read -> exact)
// Chain: qperm -> cvt_pk -> newbcast -> 8 indep MFMA -> 2 sel -> add ->
// exp2 -> add1 -> rcp -> fma  (~10 layers + MFMA block).
__global__ __launch_bounds__(64, 1) void rnn_scan(
    const float* __restrict__ xp,      // [B,S,H,D] fp32 (GEMM1 output)
    const float* __restrict__ w_h,     // [H,D,D]
    const float* __restrict__ bias,    // [H,D]
    const float* __restrict__ h0,      // [B,H,D]
    unsigned short* __restrict__ y) {  // [B,S,H,D] bf16
    const int bh = blockIdx.x;
    const int b = bh >> 4;
    const int h = bh & 15;
    const int e = threadIdx.x;
    const int c = e & 15;           // fragment column index
    const int q = e >> 4;           // 16-lane group (row)

    // ---- static W^T B-fragments under pi (group q supplies h[16q..16q+15]),
    // scaled by 2*log2e: lane (q,c) of BfA[nt] holds 2L*W[nt*16+c][16q+j],
    // BfB[nt] holds 2L*W[nt*16+c][16q+8+j], j=0..7.
    auto loadB = [&](int nt, int koff) -> bf16x8 {
        const float* wr = w_h + ((size_t)(h * 64 + nt * 16 + c)) * 64 + q * 16 + koff;
        float4 v0 = ((const float4*)wr)[0];
        float4 v1 = ((const float4*)wr)[1];
        int32x4 bi;
        bi[0] = (int)(f2bf(v0.x * TWO_LOG2E) | (f2bf(v0.y * TWO_LOG2E) << 16));
        bi[1] = (int)(f2bf(v0.z * TWO_LOG2E) | (f2bf(v0.w * TWO_LOG2E) << 16));
        bi[2] = (int)(f2bf(v1.x * TWO_LOG2E) | (f2bf(v1.y * TWO_LOG2E) << 16));
        bi[3] = (int)(f2bf(v1.w * 0.0f + v1.z * TWO_LOG2E) |
                      (f2bf(v1.w * TWO_LOG2E) << 16));
        return __builtin_bit_cast(bf16x8, bi);
    };
    const bf16x8 BfA0 = loadB(0, 0), BfB0 = loadB(0, 8);
    const bf16x8 BfA1 = loadB(1, 0), BfB1 = loadB(1, 8);
    const bf16x8 BfA2 = loadB(2, 0), BfB2 = loadB(2, 8);
    const bf16x8 BfA3 = loadB(3, 0), BfB3 = loadB(3, 8);

    const bool q1 = (q & 1) != 0;
    const bool q2 = (q & 2) != 0;

    const float be = bias[h * 64 + e];
    float hn = h0[(b * 16 + h) * 64 + e];   // f32 state, 1/lane

    const float* xb = xp + ((size_t)(b * S_) * 16 + h) * 64 + e;  // + t*1024
    unsigned short* yb = y + ((size_t)(b * S_) * 16 + h) * 64 + e;

    // prefetched 2L*(bias+x) (off the dependent path)
    float bxA[8], bxB[8];
#pragma unroll
    for (int i2 = 0; i2 < 8; i2++)
        bxA[i2] = (be + xb[(size_t)i2 * 1024]) * TWO_LOG2E;
#pragma unroll
    for (int i2 = 0; i2 < 8; i2++)
        bxB[i2] = (be + xb[(size_t)(8 + i2) * 1024]) * TWO_LOG2E;

    auto step = [&](int t, float bx) {
        // neighbor's f32 h via quad_perm [1,1,3,3] (even lane 2d gets h[2d+1])
        float hs = __builtin_bit_cast(float, __builtin_amdgcn_update_dpp(
            0, __builtin_bit_cast(int, hn), 0xF5, 0xF, 0xF, true));
        // packed bf16 pair (lo = own = h[2d], hi = neighbor = h[2d+1]); RNE.
        unsigned int pk;
        asm("v_cvt_pk_bf16_f32 %0, %1, %2" : "=v"(pk) : "v"(hn), "v"(hs));
        // row_newbcast:2d: broadcast even lane 2d's pk to the whole 16-row.
        int32x4 a0i, a1i;
        a0i[0] = __builtin_amdgcn_update_dpp(0, (int)pk, 0x150 + 0,  0xF, 0xF, true);
        a0i[1] = __builtin_amdgcn_update_dpp(0, (int)pk, 0x150 + 2,  0xF, 0xF, true);
        a0i[2] = __builtin_amdgcn_update_dpp(0, (int)pk, 0x150 + 4,  0xF, 0xF, true);
        a0i[3] = __builtin_amdgcn_update_dpp(0, (int)pk, 0x150 + 6,  0xF, 0xF, true);
        a1i[0] = __builtin_amdgcn_update_dpp(0, (int)pk, 0x150 + 8,  0xF, 0xF, true);
        a1i[1] = __builtin_amdgcn_update_dpp(0, (int)pk, 0x150 + 10, 0xF, 0xF, true);
        a1i[2] = __builtin_amdgcn_update_dpp(0, (int)pk, 0x150 + 12, 0xF, 0xF, true);
        a1i[3] = __builtin_amdgcn_update_dpp(0, (int)pk, 0x150 + 14, 0xF, 0xF, true);
        bf16x8 A0 = __builtin_bit_cast(bf16x8, a0i);   // h[16q + 0..7]
        bf16x8 A1 = __builtin_bit_cast(bf16x8, a1i);   // h[16q + 8..15]
        const floatx4 z4 = (floatx4){0.f, 0.f, 0.f, 0.f};
        const floatx4 cb = (floatx4){bx, 0.f, 0.f, 0.f};  // bx rides in C reg0
        // pre'[nt*16+c] = 2L*(W h + b + x); A-half carries bx in C.
        floatx4 acA0 = __builtin_amdgcn_mfma_f32_16x16x32_bf16(A0, BfA0, cb, 0, 0, 0);
        floatx4 acB0 = __builtin_amdgcn_mfma_f32_16x16x32_bf16(A1, BfB0, z4, 0, 0, 0);
        floatx4 acA1 = __builtin_amdgcn_mfma_f32_16x16x32_bf16(A0, BfA1, cb, 0, 0, 0);
        floatx4 acB1 = __builtin_amdgcn_mfma_f32_16x16x32_bf16(A1, BfB1, z4, 0, 0, 0);
        floatx4 acA2 = __builtin_amdgcn_mfma_f32_16x16x32_bf16(A0, BfA2, cb, 0, 0, 0);
        floatx4 acB2 = __builtin_amdgcn_mfma_f32_16x16x32_bf16(A1, BfB2, z4, 0, 0, 0);
        floatx4 acA3 = __builtin_amdgcn_mfma_f32_16x16x32_bf16(A0, BfA3, cb, 0, 0, 0);
        floatx4 acB3 = __builtin_amdgcn_mfma_f32_16x16x32_bf16(A1, BfB3, z4, 0, 0, 0);
        // lane (q,c) reads D[4q][c] (reg0) of nt=q: select + single add.
        float yA01 = q1 ? acA1[0] : acA0[0];
        float yA23 = q1 ? acA3[0] : acA2[0];
        float yA   = q2 ? yA23 : yA01;
        float yB01 = q1 ? acB1[0] : acB0[0];
        float yB23 = q1 ? acB3[0] : acB2[0];
        float yB   = q2 ? yB23 : yB01;
        float pre = yA + yB;                       // = 2*log2e * preact
        // tanh(x) = 1 - 2/(e^{2x}+1); e^{2x} = exp2(pre)
        float em = __builtin_amdgcn_exp2f(pre);
        float r  = __builtin_amdgcn_rcpf(em + 1.0f);
        hn = fmaf(-2.0f, r, 1.0f);
        // store (off the dependent path)
        yb[(size_t)t * 1024] = (unsigned short)f2bf(hn);
    };

    for (int t0 = 0; t0 < S_; t0 += 16) {
#pragma unroll
        for (int u = 0; u < 8; u++) step(t0 + u, bxA[u]);
        if (t0 + 16 < S_) {
#pragma unroll
            for (int i2 = 0; i2 < 8; i2++)
                bxA[i2] = (be + xb[(size_t)(t0 + 16 + i2) * 1024]) * TWO_LOG2E;
        }
#pragma unroll
        for (int u = 0; u < 8; u++) step(t0 + 8 + u, bxB[u]);
        if (t0 + 24 < S_) {
#pragma unroll
            for (int i2 = 0; i2 < 8; i2++)
                bxB[i2] = (be + xb[(size_t)(t0 + 24 + i2) * 1024]) * TWO_LOG2E;
        }
    }
}

extern "C" void kernel_launch(void* const* d_in, const int* in_sizes, int n_in,
                              void* d_out, int out_size, void* d_ws, size_t ws_size,
                              hipStream_t stream) {
    const float* x     = (const float*)d_in[0];  // [B,S,IN]
    const float* h0    = (const float*)d_in[1];  // [B,H,D]
    const float* w_in  = (const float*)d_in[2];  // [HD,IN]
    const float* w_h   = (const float*)d_in[3];  // [H,D,D]
    const float* bias  = (const float*)d_in[4];  // [H,D]
    const float* w_out = (const float*)d_in[5];  // [OUT,HD]
    float* out = (float*)d_out;                  // [B,S,OUT] fp32; doubles as xp scratch

    char* ws = (char*)d_ws;
    unsigned short* x_bf    = (unsigned short*)(ws);                       // 33.5 MB
    unsigned short* win_bf  = (unsigned short*)(ws + (size_t)33554432);    // 2 MB
    unsigned short* wout_bf = (unsigned short*)(ws + (size_t)35651584);    // 2 MB
    unsigned short* y_bf    = (unsigned short*)(ws + (size_t)37748736);    // 33.5 MB

    {
        int n4 = (M_ * IN_) / 4;
        cast_f32_bf16<<<(n4 + 255) / 256, 256, 0, stream>>>(x, x_bf, n4);
        int w4 = (HD_ * IN_) / 4;
        cast_f32_bf16<<<(w4 + 255) / 256, 256, 0, stream>>>(w_in, win_bf, w4);
        cast_f32_bf16<<<(w4 + 255) / 256, 256, 0, stream>>>(w_out, wout_bf, w4);
    }
    // GEMM1: xp = x @ w_in^T  -> stored in d_out as scratch
    dim3 g1(HD_ / 128, M_ / 128);
    gemm_bt<<<g1, 256, 0, stream>>>(x_bf, win_bf, out, M_, HD_, IN_);
    // sequential scan: reads xp (d_out), writes y_bf (64 chains, 1 wave/CU)
    rnn_scan<<<64, 64, 0, stream>>>(out, w_h, bias, h0, y_bf);
    // GEMM2: out = y @ w_out^T  -> overwrites d_out
    dim3 g2(OUT_ / 128, M_ / 128);
    gemm_bt<<<g2, 256, 0, stream>>>(y_bf, wout_bf, out, M_, OUT_, HD_);
}

// Round 7
// 959.529 us; speedup vs baseline: 2.9515x; 1.0015x over previous
//
#include <hip/hip_runtime.h>

#define B_ 4
#define S_ 4096
#define IN_ 1024
#define H_ 16
#define D_ 64
#define OUT_ 1024
#define HD_ 1024   // H*D
#define M_ 16384   // B*S

typedef __bf16 bf16x8 __attribute__((ext_vector_type(8)));
typedef __bf16 bf16x2 __attribute__((ext_vector_type(2)));
typedef float floatx4 __attribute__((ext_vector_type(4)));
typedef int int32x4 __attribute__((ext_vector_type(4)));

#define TWO_LOG2E 2.885390081777927f   // 2*log2(e)

static __device__ __forceinline__ unsigned int f2bf(float f) {
    unsigned int u = __builtin_bit_cast(unsigned int, f);
    u += 0x7fffu + ((u >> 16) & 1u);   // round-to-nearest-even
    return u >> 16;
}

// ---------------- cast fp32 -> bf16, vectorized x4 ----------------
__global__ void cast_f32_bf16(const float* __restrict__ src,
                              unsigned short* __restrict__ dst, int n4) {
    int i = blockIdx.x * blockDim.x + threadIdx.x;
    if (i < n4) {
        float4 v = ((const float4*)src)[i];
        ushort4 o;
        o.x = (unsigned short)f2bf(v.x); o.y = (unsigned short)f2bf(v.y);
        o.z = (unsigned short)f2bf(v.z); o.w = (unsigned short)f2bf(v.w);
        ((ushort4*)dst)[i] = o;
    }
}

// ---------------- bf16 MFMA GEMM: C[M,N] = A[M,K] * B[N,K]^T ----------------
// v2 (this round): m97-structure staging — global_load_lds width=16 into
// LINEAR [128][32] LDS (no pad). chunk = 16 rows = 1024B = one wave-load:
// LDS slot = chunk*1024 + lane*16  ==  row(=chunk*16+(lane>>2))*64 + (lane&3)*16.
// Replaces flat-load+VGPR round-trip (Common-mistake #1; m193 +67%, m151).
__global__ __launch_bounds__(256) void gemm_bt(
    const unsigned short* __restrict__ A,   // [M,K] bf16
    const unsigned short* __restrict__ Bm,  // [N,K] bf16
    float* __restrict__ C, int M, int N, int K) {
    __shared__ unsigned short As[128 * 32];
    __shared__ unsigned short Bs[128 * 32];
    const int t = threadIdx.x;
    const int lane = t & 63;
    const int wave = t >> 6;
    const int wm = wave >> 1, wn = wave & 1;
    const int m0 = blockIdx.y * 128;
    const int n0 = blockIdx.x * 128;
    const int l16 = lane & 15;
    const int quad = lane >> 4;
    const int r16 = lane >> 2;      // row within 16-row chunk
    const int kc = lane & 3;        // 8-ushort k-slot within row

    floatx4 acc[4][4];
#pragma unroll
    for (int i = 0; i < 4; i++)
#pragma unroll
        for (int j = 0; j < 4; j++) acc[i][j] = (floatx4){0.f, 0.f, 0.f, 0.f};

    for (int k0 = 0; k0 < K; k0 += 32) {
        // stage A,B tiles: 8 chunks each, wave w owns chunks 2w, 2w+1
#pragma unroll
        for (int it = 0; it < 2; it++) {
            int chunk = wave * 2 + it;              // 0..7
            int row = chunk * 16 + r16;
            const unsigned short* ga = A + (size_t)(m0 + row) * K + k0 + kc * 8;
            __builtin_amdgcn_global_load_lds(
                (const __attribute__((address_space(1))) void*)ga,
                (__attribute__((address_space(3))) void*)(As + chunk * 512),
                16, 0, 0);
            const unsigned short* gb = Bm + (size_t)(n0 + row) * K + k0 + kc * 8;
            __builtin_amdgcn_global_load_lds(
                (const __attribute__((address_space(1))) void*)gb,
                (__attribute__((address_space(3))) void*)(Bs + chunk * 512),
                16, 0, 0);
        }
        __syncthreads();
        bf16x8 af[4], bfr[4];
#pragma unroll
        for (int i = 0; i < 4; i++)
            af[i] = *(const bf16x8*)(As + (wm * 64 + i * 16 + l16) * 32 + quad * 8);
#pragma unroll
        for (int j = 0; j < 4; j++)
            bfr[j] = *(const bf16x8*)(Bs + (wn * 64 + j * 16 + l16) * 32 + quad * 8);
#pragma unroll
        for (int i = 0; i < 4; i++)
#pragma unroll
            for (int j = 0; j < 4; j++)
                acc[i][j] = __builtin_amdgcn_mfma_f32_16x16x32_bf16(
                    af[i], bfr[j], acc[i][j], 0, 0, 0);
        __syncthreads();
    }
#pragma unroll
    for (int i = 0; i < 4; i++)
#pragma unroll
        for (int j = 0; j < 4; j++)
#pragma unroll
            for (int r = 0; r < 4; r++) {
                int row = m0 + wm * 64 + i * 16 + quad * 4 + r;
                int col = n0 + wn * 64 + j * 16 + l16;
                C[(size_t)row * N + col] = acc[i][j][r];
            }
}

// ---------------- sequential RNN scan (v11: short-chain step) ---------------
// 64 blocks (one (b,h) chain), ONE wave, 1 wave/CU. Measured 415 cyc/step;
// issue = 46 VALU + 32 MFMA cyc, stall = 337 (dependent-op latency floor).
// Chain: qperm -> cvt_pk -> newbcast -> 8 indep MFMA -> 2 sel -> add ->
// exp2 -> add1 -> rcp -> fma.
__global__ __launch_bounds__(64, 1) void rnn_scan(
    const float* __restrict__ xp,      // [B,S,H,D] fp32 (GEMM1 output)
    const float* __restrict__ w_h,     // [H,D,D]
    const float* __restrict__ bias,    // [H,D]
    const float* __restrict__ h0,      // [B,H,D]
    unsigned short* __restrict__ y) {  // [B,S,H,D] bf16
    const int bh = blockIdx.x;
    const int b = bh >> 4;
    const int h = bh & 15;
    const int e = threadIdx.x;
    const int c = e & 15;           // fragment column index
    const int q = e >> 4;           // 16-lane group (row)

    // ---- static W^T B-fragments under pi (group q supplies h[16q..16q+15]),
    // scaled by 2*log2e: lane (q,c) of BfA[nt] holds 2L*W[nt*16+c][16q+j],
    // BfB[nt] holds 2L*W[nt*16+c][16q+8+j], j=0..7.
    auto loadB = [&](int nt, int koff) -> bf16x8 {
        const float* wr = w_h + ((size_t)(h * 64 + nt * 16 + c)) * 64 + q * 16 + koff;
        float4 v0 = ((const float4*)wr)[0];
        float4 v1 = ((const float4*)wr)[1];
        int32x4 bi;
        bi[0] = (int)(f2bf(v0.x * TWO_LOG2E) | (f2bf(v0.y * TWO_LOG2E) << 16));
        bi[1] = (int)(f2bf(v0.z * TWO_LOG2E) | (f2bf(v0.w * TWO_LOG2E) << 16));
        bi[2] = (int)(f2bf(v1.x * TWO_LOG2E) | (f2bf(v1.y * TWO_LOG2E) << 16));
        bi[3] = (int)(f2bf(v1.z * TWO_LOG2E) | (f2bf(v1.w * TWO_LOG2E) << 16));
        return __builtin_bit_cast(bf16x8, bi);
    };
    const bf16x8 BfA0 = loadB(0, 0), BfB0 = loadB(0, 8);
    const bf16x8 BfA1 = loadB(1, 0), BfB1 = loadB(1, 8);
    const bf16x8 BfA2 = loadB(2, 0), BfB2 = loadB(2, 8);
    const bf16x8 BfA3 = loadB(3, 0), BfB3 = loadB(3, 8);

    const bool q1 = (q & 1) != 0;
    const bool q2 = (q & 2) != 0;

    const float be = bias[h * 64 + e];
    float hn = h0[(b * 16 + h) * 64 + e];   // f32 state, 1/lane

    const float* xb = xp + ((size_t)(b * S_) * 16 + h) * 64 + e;  // + t*1024
    unsigned short* yb = y + ((size_t)(b * S_) * 16 + h) * 64 + e;

    // prefetched 2L*(bias+x) (off the dependent path)
    float bxA[8], bxB[8];
#pragma unroll
    for (int i2 = 0; i2 < 8; i2++)
        bxA[i2] = (be + xb[(size_t)i2 * 1024]) * TWO_LOG2E;
#pragma unroll
    for (int i2 = 0; i2 < 8; i2++)
        bxB[i2] = (be + xb[(size_t)(8 + i2) * 1024]) * TWO_LOG2E;

    auto step = [&](int t, float bx) {
        // neighbor's f32 h via quad_perm [1,1,3,3] (even lane 2d gets h[2d+1])
        float hs = __builtin_bit_cast(float, __builtin_amdgcn_update_dpp(
            0, __builtin_bit_cast(int, hn), 0xF5, 0xF, 0xF, true));
        // packed bf16 pair (lo = own = h[2d], hi = neighbor = h[2d+1]); RNE.
        unsigned int pk;
        asm("v_cvt_pk_bf16_f32 %0, %1, %2" : "=v"(pk) : "v"(hn), "v"(hs));
        // row_newbcast:2d: broadcast even lane 2d's pk to the whole 16-row.
        int32x4 a0i, a1i;
        a0i[0] = __builtin_amdgcn_update_dpp(0, (int)pk, 0x150 + 0,  0xF, 0xF, true);
        a0i[1] = __builtin_amdgcn_update_dpp(0, (int)pk, 0x150 + 2,  0xF, 0xF, true);
        a0i[2] = __builtin_amdgcn_update_dpp(0, (int)pk, 0x150 + 4,  0xF, 0xF, true);
        a0i[3] = __builtin_amdgcn_update_dpp(0, (int)pk, 0x150 + 6,  0xF, 0xF, true);
        a1i[0] = __builtin_amdgcn_update_dpp(0, (int)pk, 0x150 + 8,  0xF, 0xF, true);
        a1i[1] = __builtin_amdgcn_update_dpp(0, (int)pk, 0x150 + 10, 0xF, 0xF, true);
        a1i[2] = __builtin_amdgcn_update_dpp(0, (int)pk, 0x150 + 12, 0xF, 0xF, true);
        a1i[3] = __builtin_amdgcn_update_dpp(0, (int)pk, 0x150 + 14, 0xF, 0xF, true);
        bf16x8 A0 = __builtin_bit_cast(bf16x8, a0i);   // h[16q + 0..7]
        bf16x8 A1 = __builtin_bit_cast(bf16x8, a1i);   // h[16q + 8..15]
        const floatx4 z4 = (floatx4){0.f, 0.f, 0.f, 0.f};
        const floatx4 cb = (floatx4){bx, 0.f, 0.f, 0.f};  // bx rides in C reg0
        // pre'[nt*16+c] = 2L*(W h + b + x); A-half carries bx in C.
        floatx4 acA0 = __builtin_amdgcn_mfma_f32_16x16x32_bf16(A0, BfA0, cb, 0, 0, 0);
        floatx4 acB0 = __builtin_amdgcn_mfma_f32_16x16x32_bf16(A1, BfB0, z4, 0, 0, 0);
        floatx4 acA1 = __builtin_amdgcn_mfma_f32_16x16x32_bf16(A0, BfA1, cb, 0, 0, 0);
        floatx4 acB1 = __builtin_amdgcn_mfma_f32_16x16x32_bf16(A1, BfB1, z4, 0, 0, 0);
        floatx4 acA2 = __builtin_amdgcn_mfma_f32_16x16x32_bf16(A0, BfA2, cb, 0, 0, 0);
        floatx4 acB2 = __builtin_amdgcn_mfma_f32_16x16x32_bf16(A1, BfB2, z4, 0, 0, 0);
        floatx4 acA3 = __builtin_amdgcn_mfma_f32_16x16x32_bf16(A0, BfA3, cb, 0, 0, 0);
        floatx4 acB3 = __builtin_amdgcn_mfma_f32_16x16x32_bf16(A1, BfB3, z4, 0, 0, 0);
        // lane (q,c) reads D[4q][c] (reg0) of nt=q: select + single add.
        float yA01 = q1 ? acA1[0] : acA0[0];
        float yA23 = q1 ? acA3[0] : acA2[0];
        float yA   = q2 ? yA23 : yA01;
        float yB01 = q1 ? acB1[0] : acB0[0];
        float yB23 = q1 ? acB3[0] : acB2[0];
        float yB   = q2 ? yB23 : yB01;
        float pre = yA + yB;                       // = 2*log2e * preact
        // tanh(x) = 1 - 2/(e^{2x}+1); e^{2x} = exp2(pre)
        float em = __builtin_amdgcn_exp2f(pre);
        float r  = __builtin_amdgcn_rcpf(em + 1.0f);
        hn = fmaf(-2.0f, r, 1.0f);
        // store (off the dependent path)
        yb[(size_t)t * 1024] = (unsigned short)f2bf(hn);
    };

    for (int t0 = 0; t0 < S_; t0 += 16) {
#pragma unroll
        for (int u = 0; u < 8; u++) step(t0 + u, bxA[u]);
        if (t0 + 16 < S_) {
#pragma unroll
            for (int i2 = 0; i2 < 8; i2++)
                bxA[i2] = (be + xb[(size_t)(t0 + 16 + i2) * 1024]) * TWO_LOG2E;
        }
#pragma unroll
        for (int u = 0; u < 8; u++) step(t0 + 8 + u, bxB[u]);
        if (t0 + 24 < S_) {
#pragma unroll
            for (int i2 = 0; i2 < 8; i2++)
                bxB[i2] = (be + xb[(size_t)(t0 + 24 + i2) * 1024]) * TWO_LOG2E;
        }
    }
}

extern "C" void kernel_launch(void* const* d_in, const int* in_sizes, int n_in,
                              void* d_out, int out_size, void* d_ws, size_t ws_size,
                              hipStream_t stream) {
    const float* x     = (const float*)d_in[0];  // [B,S,IN]
    const float* h0    = (const float*)d_in[1];  // [B,H,D]
    const float* w_in  = (const float*)d_in[2];  // [HD,IN]
    const float* w_h   = (const float*)d_in[3];  // [H,D,D]
    const float* bias  = (const float*)d_in[4];  // [H,D]
    const float* w_out = (const float*)d_in[5];  // [OUT,HD]
    float* out = (float*)d_out;                  // [B,S,OUT] fp32; doubles as xp scratch

    char* ws = (char*)d_ws;
    unsigned short* x_bf    = (unsigned short*)(ws);                       // 33.5 MB
    unsigned short* win_bf  = (unsigned short*)(ws + (size_t)33554432);    // 2 MB
    unsigned short* wout_bf = (unsigned short*)(ws + (size_t)35651584);    // 2 MB
    unsigned short* y_bf    = (unsigned short*)(ws + (size_t)37748736);    // 33.5 MB

    {
        int n4 = (M_ * IN_) / 4;
        cast_f32_bf16<<<(n4 + 255) / 256, 256, 0, stream>>>(x, x_bf, n4);
        int w4 = (HD_ * IN_) / 4;
        cast_f32_bf16<<<(w4 + 255) / 256, 256, 0, stream>>>(w_in, win_bf, w4);
        cast_f32_bf16<<<(w4 + 255) / 256, 256, 0, stream>>>(w_out, wout_bf, w4);
    }
    // GEMM1: xp = x @ w_in^T  -> stored in d_out as scratch
    dim3 g1(HD_ / 128, M_ / 128);
    gemm_bt<<<g1, 256, 0, stream>>>(x_bf, win_bf, out, M_, HD_, IN_);
    // sequential scan: reads xp (d_out), writes y_bf (64 chains, 1 wave/CU)
    rnn_scan<<<64, 64, 0, stream>>>(out, w_h, bias, h0, y_bf);
    // GEMM2: out = y @ w_out^T  -> overwrites d_out
    dim3 g2(OUT_ / 128, M_ / 128);
    gemm_bt<<<g2, 256, 0, stream>>>(y_bf, wout_bf, out, M_, OUT_, HD_);
}